// Round 1
// baseline (1233.776 us; speedup 1.0000x reference)
//
#include <hip/hip_runtime.h>
#include <hip/hip_bf16.h>

#define F_IN 128
#define H 64
#define NH 4

// ---------------------------------------------------------------------------
// K1a: Wh_all[h][i][f] = sum_k x[i][k] * w_heads[h][k][f]
// one block per row i, 256 threads = 4 heads x 64 features
__global__ void wh_kernel(const float* __restrict__ x,
                          const float* __restrict__ w_heads,
                          float* __restrict__ Wh_all, int N) {
    int i = blockIdx.x;
    int tid = threadIdx.x;
    int h = tid >> 6, f = tid & 63;
    __shared__ float xs[F_IN];
    if (tid < F_IN) xs[tid] = x[(size_t)i * F_IN + tid];
    __syncthreads();
    float acc = 0.f;
    const float* w = w_heads + (size_t)h * F_IN * H + f;
#pragma unroll 8
    for (int k = 0; k < F_IN; ++k) acc += xs[k] * w[(size_t)k * H];
    Wh_all[((size_t)h * N + i) * H + f] = acc;
}

// K1b: x_res[i][f] = sum_k x[i][k] * lin_w[f][k] + lin_b[f]
__global__ void xres_kernel(const float* __restrict__ x,
                            const float* __restrict__ lin_w,
                            const float* __restrict__ lin_b,
                            float* __restrict__ x_res, int N) {
    int tid = threadIdx.x;
    int f = tid & 63, rl = tid >> 6;
    int i = blockIdx.x * 4 + rl;
    __shared__ float xs[4][F_IN];
#pragma unroll
    for (int rep = 0; rep < 2; ++rep) {
        int idx = rep * 256 + tid;
        xs[idx >> 7][idx & 127] =
            x[(size_t)(blockIdx.x * 4 + (idx >> 7)) * F_IN + (idx & 127)];
    }
    __syncthreads();
    float acc = lin_b[f];
#pragma unroll 8
    for (int k = 0; k < F_IN; ++k) acc += xs[rl][k] * lin_w[(size_t)f * F_IN + k];
    x_res[(size_t)i * H + f] = acc;
}

// K2: s1[h][i] = Wh[h][i][:] . a[h][0:64],  s2[h][i] = Wh[h][i][:] . a[h][64:128]
__global__ void scores_kernel(const float* __restrict__ Wh,
                              const float* __restrict__ a,
                              float* __restrict__ s1, float* __restrict__ s2,
                              int N, int nh) {
    int idx = blockIdx.x * blockDim.x + threadIdx.x;
    if (idx >= nh * N) return;
    int h = idx / N, i = idx - h * N;
    const float* row = Wh + ((size_t)h * N + i) * H;
    const float* a1 = a + (size_t)h * 2 * H;
    const float* a2 = a1 + H;
    float acc1 = 0.f, acc2 = 0.f;
#pragma unroll 8
    for (int f = 0; f < H; ++f) {
        float v = row[f];
        acc1 += v * a1[f];
        acc2 += v * a2[f];
    }
    s1[(size_t)h * N + i] = acc1;
    s2[(size_t)h * N + i] = acc2;
}

// K3: per-row masked-softmax stats (max m, sumexp l), NHD heads in one adj pass
template <int NHD>
__global__ void row_stats_kernel(const int* __restrict__ adj,
                                 const float* __restrict__ s1,
                                 const float* __restrict__ s2,
                                 float* __restrict__ m_out,
                                 float* __restrict__ l_out, int N) {
    int i = blockIdx.x;
    int tid = threadIdx.x;
    float s1v[NHD], m[NHD], l[NHD];
#pragma unroll
    for (int h = 0; h < NHD; ++h) {
        s1v[h] = s1[(size_t)h * N + i];
        m[h] = -9e15f;
        l[h] = 0.f;
    }
    const int* arow = adj + (size_t)i * N;
    for (int j = tid; j < N; j += 256) {
        if (arow[j] > 0) {
#pragma unroll
            for (int h = 0; h < NHD; ++h) {
                float t = s1v[h] + s2[(size_t)h * N + j];
                t = t > 0.f ? t : 0.2f * t;
                float mn = fmaxf(m[h], t);
                l[h] = l[h] * __expf(m[h] - mn) + __expf(t - mn);
                m[h] = mn;
            }
        }
    }
    // wave (64) reduction, then cross-wave via LDS
#pragma unroll
    for (int off = 32; off > 0; off >>= 1) {
#pragma unroll
        for (int h = 0; h < NHD; ++h) {
            float mo = __shfl_down(m[h], off, 64);
            float lo = __shfl_down(l[h], off, 64);
            float mn = fmaxf(m[h], mo);
            l[h] = l[h] * __expf(m[h] - mn) + lo * __expf(mo - mn);
            m[h] = mn;
        }
    }
    __shared__ float sm[NHD][4], sl[NHD][4];
    int wave = tid >> 6, lane = tid & 63;
    if (lane == 0)
#pragma unroll
        for (int h = 0; h < NHD; ++h) { sm[h][wave] = m[h]; sl[h][wave] = l[h]; }
    __syncthreads();
    if (tid == 0) {
#pragma unroll
        for (int h = 0; h < NHD; ++h) {
            float mm = -9e15f, ll = 0.f;
#pragma unroll
            for (int w = 0; w < 4; ++w) {
                float mn = fmaxf(mm, sm[h][w]);
                ll = ll * __expf(mm - mn) + sl[h][w] * __expf(sm[h][w] - mn);
                mm = mn;
            }
            m_out[(size_t)h * N + i] = mm;
            l_out[(size_t)h * N + i] = ll;
        }
    }
}

// K4: out[i][h*64+f] = elu( sum_j p(i,j) * Wh[h][j][f] ), p normalized via (m,l)
// 32 rows per block, j-chunks of 64 staged in LDS. gridDim.y = head.
__global__ void pv_kernel(const int* __restrict__ adj,
                          const float* __restrict__ Wh_all,
                          const float* __restrict__ s1a,
                          const float* __restrict__ s2a,
                          const float* __restrict__ ma,
                          const float* __restrict__ la,
                          float* __restrict__ out, int out_stride, int N) {
    int h = blockIdx.y;
    const float* Wh = Wh_all + (size_t)h * N * H;
    const float* s1 = s1a + (size_t)h * N;
    const float* s2 = s2a + (size_t)h * N;
    const float* mp = ma + (size_t)h * N;
    const float* lp = la + (size_t)h * N;
    int i0 = blockIdx.x * 32;
    int tid = threadIdx.x;
    __shared__ float Whs[64][H];
    __shared__ float ps[32][64];
    __shared__ float row_s1[32], row_m[32], row_invl[32];
    if (tid < 32) {
        int i = i0 + tid;
        row_s1[tid] = s1[i];
        row_m[tid] = mp[i];
        float lv = lp[i];
        row_invl[tid] = (lv > 0.f) ? 1.f / lv : 0.f;
    }
    float acc[8];
#pragma unroll
    for (int r = 0; r < 8; ++r) acc[r] = 0.f;
    int f = tid & 63, g = tid >> 6;
    __syncthreads();
    for (int jc = 0; jc < N; jc += 64) {
        // stage Wh chunk [64 j][64 f]
#pragma unroll
        for (int rep = 0; rep < 16; ++rep) {
            int idx = rep * 256 + tid;
            Whs[idx >> 6][idx & 63] = Wh[(size_t)(jc + (idx >> 6)) * H + (idx & 63)];
        }
        // compute normalized p chunk [32 rows][64 j]
#pragma unroll
        for (int rep = 0; rep < 8; ++rep) {
            int idx = rep * 256 + tid;
            int r = idx >> 6, j = idx & 63;
            int aj = adj[(size_t)(i0 + r) * N + jc + j];
            float p = 0.f;
            if (aj > 0) {
                float t = row_s1[r] + s2[jc + j];
                t = t > 0.f ? t : 0.2f * t;
                p = __expf(t - row_m[r]) * row_invl[r];
            }
            ps[r][j] = p;
        }
        __syncthreads();
#pragma unroll
        for (int j = 0; j < 64; ++j) {
            float w = Whs[j][f];
#pragma unroll
            for (int r = 0; r < 8; ++r) acc[r] += ps[g * 8 + r][j] * w;
        }
        __syncthreads();
    }
#pragma unroll
    for (int r = 0; r < 8; ++r) {
        int i = i0 + g * 8 + r;
        float v = acc[r];
        v = v > 0.f ? v : expm1f(v);  // ELU
        out[(size_t)i * out_stride + h * H + f] = v;
    }
}

// K5: Wh_out[i][f] = sum_k hcat[i][k] * w_out[k][f]   (K=256)
__global__ void whout_kernel(const float* __restrict__ hcat,
                             const float* __restrict__ w_out,
                             float* __restrict__ Wh_out, int N) {
    int tid = threadIdx.x;
    int f = tid & 63, rl = tid >> 6;
    int i = blockIdx.x * 4 + rl;
    __shared__ float hs[4][256];
#pragma unroll
    for (int rep = 0; rep < 4; ++rep) {
        int idx = rep * 256 + tid;
        hs[idx >> 8][idx & 255] =
            hcat[(size_t)(blockIdx.x * 4 + (idx >> 8)) * 256 + (idx & 255)];
    }
    __syncthreads();
    float acc = 0.f;
#pragma unroll 8
    for (int k = 0; k < 256; ++k) acc += hs[rl][k] * w_out[(size_t)k * H + f];
    Wh_out[(size_t)i * H + f] = acc;
}

// K9: out[i][f] = elu( sum_k (x_res[i][k]+out2[i][k]) * outlin_w[f][k] + b[f] )
__global__ void final_kernel(const float* __restrict__ x_res,
                             const float* __restrict__ out2,
                             const float* __restrict__ outlin_w,
                             const float* __restrict__ outlin_b,
                             float* __restrict__ out, int N) {
    int tid = threadIdx.x;
    int f = tid & 63, rl = tid >> 6;
    int i = blockIdx.x * 4 + rl;
    __shared__ float hs[4][H];
    hs[rl][f] = x_res[(size_t)i * H + f] + out2[(size_t)i * H + f];
    __syncthreads();
    float acc = outlin_b[f];
#pragma unroll 8
    for (int k = 0; k < H; ++k) acc += hs[rl][k] * outlin_w[(size_t)f * H + k];
    acc = acc > 0.f ? acc : expm1f(acc);
    out[(size_t)i * H + f] = acc;
}

extern "C" void kernel_launch(void* const* d_in, const int* in_sizes, int n_in,
                              void* d_out, int out_size, void* d_ws, size_t ws_size,
                              hipStream_t stream) {
    const float* x        = (const float*)d_in[0];
    const int*   adj      = (const int*)d_in[1];
    const float* w_heads  = (const float*)d_in[2];
    const float* a_heads  = (const float*)d_in[3];
    const float* w_out    = (const float*)d_in[4];
    const float* a_out    = (const float*)d_in[5];
    const float* lin_w    = (const float*)d_in[6];
    const float* lin_b    = (const float*)d_in[7];
    const float* outlin_w = (const float*)d_in[8];
    const float* outlin_b = (const float*)d_in[9];
    float* out = (float*)d_out;

    const int N = in_sizes[0] / F_IN;  // 4096

    float* ws = (float*)d_ws;
    float* Wh_all = ws;  ws += (size_t)NH * N * H;
    float* x_res  = ws;  ws += (size_t)N * H;
    float* s1h    = ws;  ws += (size_t)NH * N;
    float* s2h    = ws;  ws += (size_t)NH * N;
    float* mh     = ws;  ws += (size_t)NH * N;
    float* lh     = ws;  ws += (size_t)NH * N;
    float* hcat   = ws;  ws += (size_t)N * NH * H;
    float* Wh_out = ws;  ws += (size_t)N * H;
    float* s1o    = ws;  ws += N;
    float* s2o    = ws;  ws += N;
    float* mo     = ws;  ws += N;
    float* lo     = ws;  ws += N;
    float* out2   = ws;  ws += (size_t)N * H;

    wh_kernel<<<N, 256, 0, stream>>>(x, w_heads, Wh_all, N);
    xres_kernel<<<N / 4, 256, 0, stream>>>(x, lin_w, lin_b, x_res, N);
    scores_kernel<<<(NH * N + 255) / 256, 256, 0, stream>>>(Wh_all, a_heads, s1h, s2h, N, NH);
    row_stats_kernel<NH><<<N, 256, 0, stream>>>(adj, s1h, s2h, mh, lh, N);
    pv_kernel<<<dim3(N / 32, NH), 256, 0, stream>>>(adj, Wh_all, s1h, s2h, mh, lh,
                                                    hcat, NH * H, N);
    whout_kernel<<<N / 4, 256, 0, stream>>>(hcat, w_out, Wh_out, N);
    scores_kernel<<<(N + 255) / 256, 256, 0, stream>>>(Wh_out, a_out, s1o, s2o, N, 1);
    row_stats_kernel<1><<<N, 256, 0, stream>>>(adj, s1o, s2o, mo, lo, N);
    pv_kernel<<<dim3(N / 32, 1), 256, 0, stream>>>(adj, Wh_out, s1o, s2o, mo, lo,
                                                   out2, H, N);
    final_kernel<<<N / 4, 256, 0, stream>>>(x_res, out2, outlin_w, outlin_b, out, N);
}

// Round 2
// 461.606 us; speedup vs baseline: 2.6728x; 2.6728x over previous
//
#include <hip/hip_runtime.h>
#include <hip/hip_bf16.h>
#include <stdint.h>

#define F_IN 128
#define H 64
#define NH 4
#define LOG2E 1.44269504088896f

typedef __attribute__((ext_vector_type(8))) short bf16x8;
typedef __attribute__((ext_vector_type(4))) float floatx4;

// ---------------------------------------------------------------------------
// K0: pack adj (int 0/1) into bits. bit k of word = adj[base + k].
__global__ void pack_adj_kernel(const int* __restrict__ adj,
                                unsigned long long* __restrict__ out) {
    size_t gid = (size_t)blockIdx.x * 256 + threadIdx.x;
    int v = adj[gid];
    unsigned long long m = __ballot(v > 0);
    if ((threadIdx.x & 63) == 0) out[gid >> 6] = m;
}

// ---------------------------------------------------------------------------
// K1a: Wh_all[h][i][f] = sum_k x[i][k] * w_heads[h][k][f]
__global__ void wh_kernel(const float* __restrict__ x,
                          const float* __restrict__ w_heads,
                          float* __restrict__ Wh_all, int N) {
    int i = blockIdx.x;
    int tid = threadIdx.x;
    int h = tid >> 6, f = tid & 63;
    __shared__ float xs[F_IN];
    if (tid < F_IN) xs[tid] = x[(size_t)i * F_IN + tid];
    __syncthreads();
    float acc = 0.f;
    const float* w = w_heads + (size_t)h * F_IN * H + f;
#pragma unroll 8
    for (int k = 0; k < F_IN; ++k) acc += xs[k] * w[(size_t)k * H];
    Wh_all[((size_t)h * N + i) * H + f] = acc;
}

// K1b: x_res[i][f] = sum_k x[i][k] * lin_w[f][k] + lin_b[f]
__global__ void xres_kernel(const float* __restrict__ x,
                            const float* __restrict__ lin_w,
                            const float* __restrict__ lin_b,
                            float* __restrict__ x_res, int N) {
    int tid = threadIdx.x;
    int f = tid & 63, rl = tid >> 6;
    int i = blockIdx.x * 4 + rl;
    __shared__ float xs[4][F_IN];
#pragma unroll
    for (int rep = 0; rep < 2; ++rep) {
        int idx = rep * 256 + tid;
        xs[idx >> 7][idx & 127] =
            x[(size_t)(blockIdx.x * 4 + (idx >> 7)) * F_IN + (idx & 127)];
    }
    __syncthreads();
    float acc = lin_b[f];
#pragma unroll 8
    for (int k = 0; k < F_IN; ++k) acc += xs[rl][k] * lin_w[(size_t)f * F_IN + k];
    x_res[(size_t)i * H + f] = acc;
}

// K2: s1/s2 = Wh . a halves, pre-scaled by log2(e) for the exp2-based softmax
__global__ void scores_kernel(const float* __restrict__ Wh,
                              const float* __restrict__ a,
                              float* __restrict__ s1, float* __restrict__ s2,
                              int N, int nh) {
    int idx = blockIdx.x * blockDim.x + threadIdx.x;
    if (idx >= nh * N) return;
    int h = idx / N, i = idx - h * N;
    const float* row = Wh + ((size_t)h * N + i) * H;
    const float* a1 = a + (size_t)h * 2 * H;
    const float* a2 = a1 + H;
    float acc1 = 0.f, acc2 = 0.f;
#pragma unroll 8
    for (int f = 0; f < H; ++f) {
        float v = row[f];
        acc1 += v * a1[f];
        acc2 += v * a2[f];
    }
    s1[(size_t)h * N + i] = acc1 * LOG2E;
    s2[(size_t)h * N + i] = acc2 * LOG2E;
}

// K3: transpose + bf16-cast: src [h][N][64] f32 -> dst [h][64][N] bf16
__global__ void transpose_bf16_kernel(const float* __restrict__ src_base,
                                      unsigned short* __restrict__ dst_base,
                                      int N) {
    int h = blockIdx.y;
    int i0 = blockIdx.x * 64;
    int tid = threadIdx.x;
    __shared__ float tile[64][65];
    const float* src = src_base + ((size_t)h * N + i0) * 64;
    for (int e = tid; e < 4096; e += 256) tile[e >> 6][e & 63] = src[e];
    __syncthreads();
    unsigned short* dst = dst_base + (size_t)h * 64 * N + i0;
    for (int e = tid; e < 4096; e += 256) {
        int f = e >> 6, r = e & 63;
        __hip_bfloat16 b = __float2bfloat16(tile[r][f]);
        dst[(size_t)f * N + r] = *(unsigned short*)&b;
    }
}

// ---------------------------------------------------------------------------
// K4: fused PV via MFMA. Per wave: 16 output rows x 64 f, full K sweep.
// P generated in registers in A-frag layout; B from WhT (bf16, [h][64][N]);
// row-sums l via ones-column MFMA; normalize + ELU in epilogue.
__global__ void pv_mfma_kernel(const unsigned char* __restrict__ adjb,
                               const unsigned short* __restrict__ WhT,
                               const float* __restrict__ s1a,
                               const float* __restrict__ s2a,
                               float* __restrict__ out, int out_stride, int N) {
    const int h = blockIdx.y;
    const unsigned short* WhTh = WhT + (size_t)h * 64 * N;
    const float* s1 = s1a + (size_t)h * N;
    const float* s2 = s2a + (size_t)h * N;
    const int tid = threadIdx.x;
    const int wave = tid >> 6, lane = tid & 63;
    const int n = lane & 15, q = lane >> 4;
    const int i0 = (blockIdx.x * 4 + wave) * 16;
    const int row = i0 + n;                 // A-operand row (m = lane&15)
    const float s1v = s1[row];
    const unsigned char* arow = adjb + (size_t)row * (N >> 3);

    floatx4 acc0 = {0.f, 0.f, 0.f, 0.f};
    floatx4 acc1 = acc0, acc2 = acc0, acc3 = acc0, accl = acc0;

    bf16x8 ones;
    {
        short one = (n == 0) ? (short)0x3F80 : (short)0;
        ones[0] = one; ones[1] = one; ones[2] = one; ones[3] = one;
        ones[4] = one; ones[5] = one; ones[6] = one; ones[7] = one;
    }
    const unsigned short* b0p = WhTh + (size_t)(n) * N;
    const unsigned short* b1p = WhTh + (size_t)(16 + n) * N;
    const unsigned short* b2p = WhTh + (size_t)(32 + n) * N;
    const unsigned short* b3p = WhTh + (size_t)(48 + n) * N;

    const int KT = N >> 5;
    for (int kt = 0; kt < KT; ++kt) {
        const int jb = (kt << 5) + (q << 3);
        float4 sa = *(const float4*)(s2 + jb);
        float4 sb = *(const float4*)(s2 + jb + 4);
        unsigned int ab = arow[(kt << 2) + q];

        float e[8];
        const float* sv = (const float*)&sa;
        const float* sw = (const float*)&sb;
#pragma unroll
        for (int jj = 0; jj < 8; ++jj) {
            float t = s1v + (jj < 4 ? sv[jj] : sw[jj - 4]);
            float lr = fmaxf(t, 0.2f * t);
            lr = (ab & (1u << jj)) ? lr : -150.f;     // masked -> exp2 = 0
            e[jj] = __builtin_amdgcn_exp2f(lr);
        }
        union { unsigned int u[4]; bf16x8 v; } af;
        af.u[0] = __builtin_amdgcn_perm(__float_as_uint(e[1]), __float_as_uint(e[0]), 0x07060302u);
        af.u[1] = __builtin_amdgcn_perm(__float_as_uint(e[3]), __float_as_uint(e[2]), 0x07060302u);
        af.u[2] = __builtin_amdgcn_perm(__float_as_uint(e[5]), __float_as_uint(e[4]), 0x07060302u);
        af.u[3] = __builtin_amdgcn_perm(__float_as_uint(e[7]), __float_as_uint(e[6]), 0x07060302u);

        bf16x8 bf0 = *(const bf16x8*)(b0p + jb);
        bf16x8 bf1 = *(const bf16x8*)(b1p + jb);
        bf16x8 bf2 = *(const bf16x8*)(b2p + jb);
        bf16x8 bf3 = *(const bf16x8*)(b3p + jb);

        acc0 = __builtin_amdgcn_mfma_f32_16x16x32_bf16(af.v, bf0, acc0, 0, 0, 0);
        acc1 = __builtin_amdgcn_mfma_f32_16x16x32_bf16(af.v, bf1, acc1, 0, 0, 0);
        acc2 = __builtin_amdgcn_mfma_f32_16x16x32_bf16(af.v, bf2, acc2, 0, 0, 0);
        acc3 = __builtin_amdgcn_mfma_f32_16x16x32_bf16(af.v, bf3, acc3, 0, 0, 0);
        accl = __builtin_amdgcn_mfma_f32_16x16x32_bf16(af.v, ones, accl, 0, 0, 0);
    }

    // l[q*4+r] lives in lane (q<<4), reg r (col 0). Broadcast + invert.
    float inv[4];
#pragma unroll
    for (int r = 0; r < 4; ++r) {
        float lv = __shfl(accl[r], (q << 4), 64);
        inv[r] = 1.0f / fmaxf(lv, 1e-30f);
    }
#pragma unroll
    for (int r = 0; r < 4; ++r) {
        int i = i0 + (q << 2) + r;
        float* op = out + (size_t)i * out_stride + h * 64 + n;
        float v;
        v = acc0[r] * inv[r]; v = v > 0.f ? v : expm1f(v); op[0]  = v;
        v = acc1[r] * inv[r]; v = v > 0.f ? v : expm1f(v); op[16] = v;
        v = acc2[r] * inv[r]; v = v > 0.f ? v : expm1f(v); op[32] = v;
        v = acc3[r] * inv[r]; v = v > 0.f ? v : expm1f(v); op[48] = v;
    }
}

// K5: Wh_out[i][f] = sum_k hcat[i][k] * w_out[k][f]   (K=256)
__global__ void whout_kernel(const float* __restrict__ hcat,
                             const float* __restrict__ w_out,
                             float* __restrict__ Wh_out, int N) {
    int tid = threadIdx.x;
    int f = tid & 63, rl = tid >> 6;
    int i = blockIdx.x * 4 + rl;
    __shared__ float hs[4][256];
#pragma unroll
    for (int rep = 0; rep < 4; ++rep) {
        int idx = rep * 256 + tid;
        hs[idx >> 8][idx & 255] =
            hcat[(size_t)(blockIdx.x * 4 + (idx >> 8)) * 256 + (idx & 255)];
    }
    __syncthreads();
    float acc = 0.f;
#pragma unroll 8
    for (int k = 0; k < 256; ++k) acc += hs[rl][k] * w_out[(size_t)k * H + f];
    Wh_out[(size_t)i * H + f] = acc;
}

// K9: out[i][f] = elu( (x_res[i][:]+out2[i][:]) . outlin_w[f][:] + b[f] )
__global__ void final_kernel(const float* __restrict__ x_res,
                             const float* __restrict__ out2,
                             const float* __restrict__ outlin_w,
                             const float* __restrict__ outlin_b,
                             float* __restrict__ out, int N) {
    int tid = threadIdx.x;
    int f = tid & 63, rl = tid >> 6;
    int i = blockIdx.x * 4 + rl;
    __shared__ float hs[4][H];
    hs[rl][f] = x_res[(size_t)i * H + f] + out2[(size_t)i * H + f];
    __syncthreads();
    float acc = outlin_b[f];
#pragma unroll 8
    for (int k = 0; k < H; ++k) acc += hs[rl][k] * outlin_w[(size_t)f * H + k];
    acc = acc > 0.f ? acc : expm1f(acc);
    out[(size_t)i * H + f] = acc;
}

extern "C" void kernel_launch(void* const* d_in, const int* in_sizes, int n_in,
                              void* d_out, int out_size, void* d_ws, size_t ws_size,
                              hipStream_t stream) {
    const float* x        = (const float*)d_in[0];
    const int*   adj      = (const int*)d_in[1];
    const float* w_heads  = (const float*)d_in[2];
    const float* a_heads  = (const float*)d_in[3];
    const float* w_out    = (const float*)d_in[4];
    const float* a_out    = (const float*)d_in[5];
    const float* lin_w    = (const float*)d_in[6];
    const float* lin_b    = (const float*)d_in[7];
    const float* outlin_w = (const float*)d_in[8];
    const float* outlin_b = (const float*)d_in[9];
    float* out = (float*)d_out;

    const int N = in_sizes[0] / F_IN;  // 4096

    char* p = (char*)d_ws;
    float* hcat = (float*)p;            p += (size_t)N * 256 * 4;       // 4 MB
    float* scratch4 = (float*)p;        p += (size_t)4 * N * 64 * 4;    // 4 MB shared region
    float* x_res = (float*)p;           p += (size_t)N * 64 * 4;        // 1 MB
    float* Wh_out = (float*)p;          p += (size_t)N * 64 * 4;        // 1 MB
    float* s1h = (float*)p;             p += (size_t)NH * N * 4;        // 64 KB
    float* s2h = (float*)p;             p += (size_t)NH * N * 4;        // 64 KB
    unsigned short* WhT = (unsigned short*)p;  p += (size_t)NH * 64 * N * 2;  // 2 MB
    unsigned char* adjb = (unsigned char*)p;   p += (size_t)N * (N / 8);      // 2 MB

    // aliases inside scratch4 (Wh_all dead after transpose/scores):
    float* Wh_all = scratch4;                                   // steps 2-5
    float* out2 = scratch4;                                     // [0, 1MB)
    unsigned short* WhoT = (unsigned short*)(scratch4 + (size_t)N * 64);      // [1, 1.5MB)
    float* s1o = (float*)((char*)scratch4 + (size_t)N * 64 * 4 + (size_t)N * 64 * 2);
    float* s2o = s1o + N;

    pack_adj_kernel<<<(size_t)N * N / 256, 256, 0, stream>>>(adj, (unsigned long long*)adjb);
    wh_kernel<<<N, 256, 0, stream>>>(x, w_heads, Wh_all, N);
    xres_kernel<<<N / 4, 256, 0, stream>>>(x, lin_w, lin_b, x_res, N);
    scores_kernel<<<(NH * N + 255) / 256, 256, 0, stream>>>(Wh_all, a_heads, s1h, s2h, N, NH);
    transpose_bf16_kernel<<<dim3(N / 64, NH), 256, 0, stream>>>(Wh_all, WhT, N);
    pv_mfma_kernel<<<dim3(N / 64, NH), 256, 0, stream>>>(adjb, WhT, s1h, s2h,
                                                         hcat, NH * H, N);
    whout_kernel<<<N / 4, 256, 0, stream>>>(hcat, w_out, Wh_out, N);
    scores_kernel<<<(N + 255) / 256, 256, 0, stream>>>(Wh_out, a_out, s1o, s2o, N, 1);
    transpose_bf16_kernel<<<dim3(N / 64, 1), 256, 0, stream>>>(Wh_out, WhoT, N);
    pv_mfma_kernel<<<dim3(N / 64, 1), 256, 0, stream>>>(adjb, WhoT, s1o, s2o,
                                                        out2, H, N);
    final_kernel<<<N / 4, 256, 0, stream>>>(x_res, out2, outlin_w, outlin_b, out, N);
}

// Round 3
// 284.663 us; speedup vs baseline: 4.3342x; 1.6216x over previous
//
#include <hip/hip_runtime.h>
#include <hip/hip_bf16.h>
#include <stdint.h>

#define F_IN 128
#define H 64
#define NH 4
#define LOG2E 1.44269504088896f

typedef __attribute__((ext_vector_type(8))) short bf16x8;
typedef __attribute__((ext_vector_type(4))) float floatx4;

// ---------------------------------------------------------------------------
// K0: read adj once (64 MB), emit bitmask bytes in pv-lane order:
// adjp[(it16*KT + kt)*64 + q*16 + n] = bits for row it16*16+n, j = kt*32+q*8 .. +8
__global__ void pack_adjp_kernel(const int* __restrict__ adj,
                                 unsigned char* __restrict__ adjp, int N) {
    size_t gid = (size_t)blockIdx.x * 256 + threadIdx.x;
    int v = adj[gid];
    unsigned long long m = __ballot(v > 0);
    int lane = threadIdx.x & 63;
    if ((lane & 7) == 0) {
        int b = lane >> 3;
        size_t row = gid / N;
        int j = (int)(gid - row * N);        // = j0 + 8b for these lanes
        int kt = j >> 5, q = (j >> 3) & 3;
        int KT = N >> 5;
        adjp[((row >> 4) * (size_t)KT + kt) * 64 + q * 16 + (row & 15)] =
            (unsigned char)(m >> (b * 8));
    }
}

// ---------------------------------------------------------------------------
// K1a: Wh_all[h][i][f] = sum_k x[i][k] * w_heads[h][k][f]
__global__ void wh_kernel(const float* __restrict__ x,
                          const float* __restrict__ w_heads,
                          float* __restrict__ Wh_all, int N) {
    int i = blockIdx.x;
    int tid = threadIdx.x;
    int h = tid >> 6, f = tid & 63;
    __shared__ float xs[F_IN];
    if (tid < F_IN) xs[tid] = x[(size_t)i * F_IN + tid];
    __syncthreads();
    float acc = 0.f;
    const float* w = w_heads + (size_t)h * F_IN * H + f;
#pragma unroll 8
    for (int k = 0; k < F_IN; ++k) acc += xs[k] * w[(size_t)k * H];
    Wh_all[((size_t)h * N + i) * H + f] = acc;
}

// K1b: x_res[i][f] = sum_k x[i][k] * lin_w[f][k] + lin_b[f]
__global__ void xres_kernel(const float* __restrict__ x,
                            const float* __restrict__ lin_w,
                            const float* __restrict__ lin_b,
                            float* __restrict__ x_res, int N) {
    int tid = threadIdx.x;
    int f = tid & 63, rl = tid >> 6;
    int i = blockIdx.x * 4 + rl;
    __shared__ float xs[4][F_IN];
#pragma unroll
    for (int rep = 0; rep < 2; ++rep) {
        int idx = rep * 256 + tid;
        xs[idx >> 7][idx & 127] =
            x[(size_t)(blockIdx.x * 4 + (idx >> 7)) * F_IN + (idx & 127)];
    }
    __syncthreads();
    float acc = lin_b[f];
#pragma unroll 8
    for (int k = 0; k < F_IN; ++k) acc += xs[rl][k] * lin_w[(size_t)f * F_IN + k];
    x_res[(size_t)i * H + f] = acc;
}

// K2: s1/s2 = Wh . a halves, pre-scaled by log2(e) for exp2-based softmax
__global__ void scores_kernel(const float* __restrict__ Wh,
                              const float* __restrict__ a,
                              float* __restrict__ s1, float* __restrict__ s2,
                              int N, int nh) {
    int idx = blockIdx.x * blockDim.x + threadIdx.x;
    if (idx >= nh * N) return;
    int h = idx / N, i = idx - h * N;
    const float* row = Wh + ((size_t)h * N + i) * H;
    const float* a1 = a + (size_t)h * 2 * H;
    const float* a2 = a1 + H;
    float acc1 = 0.f, acc2 = 0.f;
#pragma unroll 8
    for (int f = 0; f < H; ++f) {
        float v = row[f];
        acc1 += v * a1[f];
        acc2 += v * a2[f];
    }
    s1[(size_t)h * N + i] = acc1 * LOG2E;
    s2[(size_t)h * N + i] = acc2 * LOG2E;
}

// K3: pack B fragments: src[h][N][64] f32 -> Bpk[h][kt][g][lane][8] bf16
// lane = q*16+n holds B[k=q*8+jj][col n] for f = g*16+n, j = kt*32+q*8+jj
__global__ void bpack_kernel(const float* __restrict__ src,
                             unsigned short* __restrict__ dst, int N) {
    int h = blockIdx.y, kt = blockIdx.x;
    int KT = N >> 5;
    int tid = threadIdx.x;
    int g = tid >> 6, lane = tid & 63;
    int q = lane >> 4, n = lane & 15;
    const float* s = src + ((size_t)h * N + kt * 32 + q * 8) * 64 + g * 16 + n;
    unsigned short tmp[8];
#pragma unroll
    for (int jj = 0; jj < 8; ++jj) {
        __hip_bfloat16 b = __float2bfloat16(s[(size_t)jj * 64]);
        tmp[jj] = *(unsigned short*)&b;
    }
    unsigned short* d = dst + (((size_t)(h * KT + kt) * 4 + g) * 64 + lane) * 8;
#pragma unroll
    for (int jj = 0; jj < 8; ++jj) d[jj] = tmp[jj];
}

// ---------------------------------------------------------------------------
// K4: fused PV via MFMA, K-split across WAVES waves, LDS-atomic reduce.
// Block covers TILES*16 rows; each wave sweeps KT/WAVES K-tiles for all rows.
template <int TILES, int WAVES>
__global__ void pv_mfma_kernel(const unsigned char* __restrict__ adjp,
                               const unsigned short* __restrict__ Bpk,
                               const float* __restrict__ s1a,
                               const float* __restrict__ s2a,
                               float* __restrict__ out, int out_stride, int N) {
    const int h = blockIdx.y;
    const int it = blockIdx.x;
    const int i0 = it * (TILES * 16);
    const int tid = threadIdx.x;
    const int wave = tid >> 6, lane = tid & 63;
    const int n = lane & 15, q = lane >> 4;
    const int KT = N >> 5;
    const int ktn = KT / WAVES;
    const int kt0 = wave * ktn;

    const float* s1 = s1a + (size_t)h * N;
    const float* s2 = s2a + (size_t)h * N;

    float s1v[TILES];
    const unsigned char* arow[TILES];
#pragma unroll
    for (int t = 0; t < TILES; ++t) {
        s1v[t] = s1[i0 + t * 16 + n];
        arow[t] = adjp + ((size_t)(it * TILES + t) * KT) * 64 + lane;
    }

    floatx4 acc[TILES][4];
    floatx4 accl[TILES];
#pragma unroll
    for (int t = 0; t < TILES; ++t) {
        accl[t] = (floatx4){0.f, 0.f, 0.f, 0.f};
#pragma unroll
        for (int g = 0; g < 4; ++g) acc[t][g] = (floatx4){0.f, 0.f, 0.f, 0.f};
    }

    bf16x8 ones;
    {
        short one = (n == 0) ? (short)0x3F80 : (short)0;
#pragma unroll
        for (int jj = 0; jj < 8; ++jj) ones[jj] = one;
    }

    const unsigned short* bbase = Bpk + (size_t)h * KT * 4 * 64 * 8 + lane * 8;

#pragma unroll 2
    for (int kt = kt0; kt < kt0 + ktn; ++kt) {
        const int jb = (kt << 5) + (q << 3);
        float4 sa = *(const float4*)(s2 + jb);
        float4 sb = *(const float4*)(s2 + jb + 4);
        const float* sv = (const float*)&sa;
        const float* sw = (const float*)&sb;

        bf16x8 bf[4];
        const unsigned short* bp = bbase + (size_t)kt * 2048;
#pragma unroll
        for (int g = 0; g < 4; ++g) bf[g] = *(const bf16x8*)(bp + g * 512);

        bf16x8 af[TILES];
#pragma unroll
        for (int t = 0; t < TILES; ++t) {
            unsigned int ab = arow[t][(size_t)kt * 64];
            float e[8];
#pragma unroll
            for (int jj = 0; jj < 8; ++jj) {
                float sj = (jj < 4 ? sv[jj] : sw[jj - 4]);
                float tt = s1v[t] + sj;
                float lr = fmaxf(tt, 0.2f * tt);
                lr = (ab & (1u << jj)) ? lr : -150.f;
                e[jj] = __builtin_amdgcn_exp2f(lr);
            }
            union { unsigned int u[4]; bf16x8 v; } u;
            u.u[0] = __builtin_amdgcn_perm(__float_as_uint(e[1]), __float_as_uint(e[0]), 0x07060302u);
            u.u[1] = __builtin_amdgcn_perm(__float_as_uint(e[3]), __float_as_uint(e[2]), 0x07060302u);
            u.u[2] = __builtin_amdgcn_perm(__float_as_uint(e[5]), __float_as_uint(e[4]), 0x07060302u);
            u.u[3] = __builtin_amdgcn_perm(__float_as_uint(e[7]), __float_as_uint(e[6]), 0x07060302u);
            af[t] = u.v;
        }

#pragma unroll
        for (int t = 0; t < TILES; ++t) {
#pragma unroll
            for (int g = 0; g < 4; ++g)
                acc[t][g] = __builtin_amdgcn_mfma_f32_16x16x32_bf16(af[t], bf[g], acc[t][g], 0, 0, 0);
            accl[t] = __builtin_amdgcn_mfma_f32_16x16x32_bf16(af[t], ones, accl[t], 0, 0, 0);
        }
    }

    // --- block-level reduction in LDS ---
    __shared__ float red[TILES * 16][64];
    __shared__ float redl[TILES * 16];
    for (int idx = tid; idx < TILES * 16 * 64; idx += WAVES * 64)
        ((float*)red)[idx] = 0.f;
    if (tid < TILES * 16) redl[tid] = 0.f;
    __syncthreads();

#pragma unroll
    for (int t = 0; t < TILES; ++t) {
#pragma unroll
        for (int g = 0; g < 4; ++g)
#pragma unroll
            for (int r = 0; r < 4; ++r)
                atomicAdd(&red[t * 16 + q * 4 + r][g * 16 + n], acc[t][g][r]);
        if (n == 0)
#pragma unroll
            for (int r = 0; r < 4; ++r)
                atomicAdd(&redl[t * 16 + q * 4 + r], accl[t][r]);
    }
    __syncthreads();

    for (int idx = tid; idx < TILES * 16 * 64; idx += WAVES * 64) {
        int row = idx >> 6, f = idx & 63;
        float lv = redl[row];
        float v = red[row][f] / fmaxf(lv, 1e-30f);
        v = v > 0.f ? v : expm1f(v);
        out[(size_t)(i0 + row) * out_stride + h * 64 + f] = v;
    }
}

// K5: Wh_out[i][f] = sum_k hcat[i][k] * w_out[k][f]   (K=256)
__global__ void whout_kernel(const float* __restrict__ hcat,
                             const float* __restrict__ w_out,
                             float* __restrict__ Wh_out, int N) {
    int tid = threadIdx.x;
    int f = tid & 63, rl = tid >> 6;
    int i = blockIdx.x * 4 + rl;
    __shared__ float hs[4][256];
#pragma unroll
    for (int rep = 0; rep < 4; ++rep) {
        int idx = rep * 256 + tid;
        hs[idx >> 8][idx & 255] =
            hcat[(size_t)(blockIdx.x * 4 + (idx >> 8)) * 256 + (idx & 255)];
    }
    __syncthreads();
    float acc = 0.f;
#pragma unroll 8
    for (int k = 0; k < 256; ++k) acc += hs[rl][k] * w_out[(size_t)k * H + f];
    Wh_out[(size_t)i * H + f] = acc;
}

// K9: out[i][f] = elu( (x_res[i][:]+out2[i][:]) . outlin_w[f][:] + b[f] )
__global__ void final_kernel(const float* __restrict__ x_res,
                             const float* __restrict__ out2,
                             const float* __restrict__ outlin_w,
                             const float* __restrict__ outlin_b,
                             float* __restrict__ out, int N) {
    int tid = threadIdx.x;
    int f = tid & 63, rl = tid >> 6;
    int i = blockIdx.x * 4 + rl;
    __shared__ float hs[4][H];
    hs[rl][f] = x_res[(size_t)i * H + f] + out2[(size_t)i * H + f];
    __syncthreads();
    float acc = outlin_b[f];
#pragma unroll 8
    for (int k = 0; k < H; ++k) acc += hs[rl][k] * outlin_w[(size_t)f * H + k];
    acc = acc > 0.f ? acc : expm1f(acc);
    out[(size_t)i * H + f] = acc;
}

extern "C" void kernel_launch(void* const* d_in, const int* in_sizes, int n_in,
                              void* d_out, int out_size, void* d_ws, size_t ws_size,
                              hipStream_t stream) {
    const float* x        = (const float*)d_in[0];
    const int*   adj      = (const int*)d_in[1];
    const float* w_heads  = (const float*)d_in[2];
    const float* a_heads  = (const float*)d_in[3];
    const float* w_out    = (const float*)d_in[4];
    const float* a_out    = (const float*)d_in[5];
    const float* lin_w    = (const float*)d_in[6];
    const float* lin_b    = (const float*)d_in[7];
    const float* outlin_w = (const float*)d_in[8];
    const float* outlin_b = (const float*)d_in[9];
    float* out = (float*)d_out;

    const int N = in_sizes[0] / F_IN;  // 4096
    const int KT = N >> 5;             // 128

    char* p = (char*)d_ws;
    float* hcat   = (float*)p;  p += (size_t)N * 256 * 4;          // 4 MB
    float* Wh_all = (float*)p;  p += (size_t)NH * N * 64 * 4;      // 4 MB
    float* x_res  = (float*)p;  p += (size_t)N * 64 * 4;           // 1 MB
    float* Wh_out = (float*)p;  p += (size_t)N * 64 * 4;           // 1 MB
    float* out2   = (float*)p;  p += (size_t)N * 64 * 4;           // 1 MB
    float* s1h    = (float*)p;  p += (size_t)NH * N * 4;
    float* s2h    = (float*)p;  p += (size_t)NH * N * 4;
    float* s1o    = (float*)p;  p += (size_t)N * 4;
    float* s2o    = (float*)p;  p += (size_t)N * 4;
    unsigned short* Bpk  = (unsigned short*)p;  p += (size_t)NH * KT * 4 * 64 * 8 * 2;  // 2 MB
    unsigned short* BpkO = (unsigned short*)p;  p += (size_t)KT * 4 * 64 * 8 * 2;       // 512 KB
    unsigned char* adjp  = (unsigned char*)p;   p += (size_t)(N / 16) * KT * 64;        // 2 MB

    pack_adjp_kernel<<<(size_t)N * N / 256, 256, 0, stream>>>(adj, adjp, N);
    wh_kernel<<<N, 256, 0, stream>>>(x, w_heads, Wh_all, N);
    xres_kernel<<<N / 4, 256, 0, stream>>>(x, lin_w, lin_b, x_res, N);
    scores_kernel<<<(NH * N + 255) / 256, 256, 0, stream>>>(Wh_all, a_heads, s1h, s2h, N, NH);
    bpack_kernel<<<dim3(KT, NH), 256, 0, stream>>>(Wh_all, Bpk, N);
    pv_mfma_kernel<2, 8><<<dim3(N / 32, NH), 512, 0, stream>>>(adjp, Bpk, s1h, s2h,
                                                               hcat, NH * H, N);
    whout_kernel<<<N / 4, 256, 0, stream>>>(hcat, w_out, Wh_out, N);
    scores_kernel<<<(N + 255) / 256, 256, 0, stream>>>(Wh_out, a_out, s1o, s2o, N, 1);
    bpack_kernel<<<dim3(KT, 1), 256, 0, stream>>>(Wh_out, BpkO, N);
    pv_mfma_kernel<1, 8><<<dim3(N / 16, 1), 512, 0, stream>>>(adjp, BpkO, s1o, s2o,
                                                              out2, H, N);
    final_kernel<<<N / 4, 256, 0, stream>>>(x_res, out2, outlin_w, outlin_b, out, N);
}

// Round 4
// 283.933 us; speedup vs baseline: 4.3453x; 1.0026x over previous
//
#include <hip/hip_runtime.h>
#include <hip/hip_bf16.h>
#include <stdint.h>

#define F_IN 128
#define H 64
#define NH 4
#define LOG2E 1.44269504088896f

typedef __attribute__((ext_vector_type(8))) short bf16x8;
typedef __attribute__((ext_vector_type(4))) float floatx4;

// ---------------------------------------------------------------------------
// K0: read adj once (64 MB), emit bitmask bytes in pv-lane order:
// adjp[(it16*KT + kt)*64 + q*16 + n] = bits for row it16*16+n, j = kt*32+q*8 .. +8
__global__ void pack_adjp_kernel(const int* __restrict__ adj,
                                 unsigned char* __restrict__ adjp, int N) {
    size_t gid = (size_t)blockIdx.x * 256 + threadIdx.x;
    int v = adj[gid];
    unsigned long long m = __ballot(v > 0);
    int lane = threadIdx.x & 63;
    if ((lane & 7) == 0) {
        int b = lane >> 3;
        size_t row = gid / N;
        int j = (int)(gid - row * N);
        int kt = j >> 5, q = (j >> 3) & 3;
        int KT = N >> 5;
        adjp[((row >> 4) * (size_t)KT + kt) * 64 + q * 16 + (row & 15)] =
            (unsigned char)(m >> (b * 8));
    }
}

// ---------------------------------------------------------------------------
// K1a: Wh_all[h][i][f], 8 rows per block (weight reuse x8)
__global__ void wh_kernel(const float* __restrict__ x,
                          const float* __restrict__ w_heads,
                          float* __restrict__ Wh_all, int N) {
    int tid = threadIdx.x;
    int h = tid >> 6, f = tid & 63;
    int i0 = blockIdx.x * 8;
    __shared__ float xs[8][F_IN];
    for (int e = tid; e < 8 * F_IN; e += 256)
        xs[e >> 7][e & 127] = x[(size_t)(i0 + (e >> 7)) * F_IN + (e & 127)];
    __syncthreads();
    float acc[8];
#pragma unroll
    for (int r = 0; r < 8; ++r) acc[r] = 0.f;
    const float* w = w_heads + (size_t)h * F_IN * H + f;
#pragma unroll 4
    for (int k = 0; k < F_IN; ++k) {
        float wv = w[(size_t)k * H];
#pragma unroll
        for (int r = 0; r < 8; ++r) acc[r] += xs[r][k] * wv;
    }
#pragma unroll
    for (int r = 0; r < 8; ++r)
        Wh_all[((size_t)h * N + i0 + r) * H + f] = acc[r];
}

// K1b: x_res = x @ lin_w^T + lin_b, 8 rows per block
__global__ void xres_kernel(const float* __restrict__ x,
                            const float* __restrict__ lin_w,
                            const float* __restrict__ lin_b,
                            float* __restrict__ x_res, int N) {
    int tid = threadIdx.x;
    int f = tid & 63, rl = tid >> 6;
    int i0 = blockIdx.x * 8;
    __shared__ float xs[8][F_IN];
    for (int e = tid; e < 8 * F_IN; e += 256)
        xs[e >> 7][e & 127] = x[(size_t)(i0 + (e >> 7)) * F_IN + (e & 127)];
    __syncthreads();
    float a0 = 0.f, a1 = 0.f;
#pragma unroll 4
    for (int k = 0; k < F_IN; ++k) {
        float wv = lin_w[(size_t)f * F_IN + k];
        a0 += xs[rl][k] * wv;
        a1 += xs[rl + 4][k] * wv;
    }
    float b = lin_b[f];
    x_res[(size_t)(i0 + rl) * H + f] = a0 + b;
    x_res[(size_t)(i0 + rl + 4) * H + f] = a1 + b;
}

// K2: s1/s2 = Wh . a halves, pre-scaled by log2(e)
__global__ void scores_kernel(const float* __restrict__ Wh,
                              const float* __restrict__ a,
                              float* __restrict__ s1, float* __restrict__ s2,
                              int N, int nh) {
    int idx = blockIdx.x * blockDim.x + threadIdx.x;
    if (idx >= nh * N) return;
    int h = idx / N, i = idx - h * N;
    const float* row = Wh + ((size_t)h * N + i) * H;
    const float* a1 = a + (size_t)h * 2 * H;
    const float* a2 = a1 + H;
    float acc1 = 0.f, acc2 = 0.f;
#pragma unroll 8
    for (int f = 0; f < H; ++f) {
        float v = row[f];
        acc1 += v * a1[f];
        acc2 += v * a2[f];
    }
    s1[(size_t)h * N + i] = acc1 * LOG2E;
    s2[(size_t)h * N + i] = acc2 * LOG2E;
}

// K3: pack B fragments: src[h][N][64] f32 -> Bpk[h][kt][g][lane][8] bf16
__global__ void bpack_kernel(const float* __restrict__ src,
                             unsigned short* __restrict__ dst, int N) {
    int h = blockIdx.y, kt = blockIdx.x;
    int KT = N >> 5;
    int tid = threadIdx.x;
    int g = tid >> 6, lane = tid & 63;
    int q = lane >> 4, n = lane & 15;
    const float* s = src + ((size_t)h * N + kt * 32 + q * 8) * 64 + g * 16 + n;
    unsigned short tmp[8];
#pragma unroll
    for (int jj = 0; jj < 8; ++jj) {
        __hip_bfloat16 b = __float2bfloat16(s[(size_t)jj * 64]);
        tmp[jj] = *(unsigned short*)&b;
    }
    unsigned short* d = dst + (((size_t)(h * KT + kt) * 4 + g) * 64 + lane) * 8;
#pragma unroll
    for (int jj = 0; jj < 8; ++jj) d[jj] = tmp[jj];
}

// ---------------------------------------------------------------------------
// K4: fused PV via MFMA, K-split across WAVES waves, explicit 1-deep prefetch,
// LDS-atomic reduce (stride-65 padded).
template <int TILES, int WAVES>
__global__ __launch_bounds__(WAVES * 64, 4)
void pv_mfma_kernel(const unsigned char* __restrict__ adjp,
                    const unsigned short* __restrict__ Bpk,
                    const float* __restrict__ s1a,
                    const float* __restrict__ s2a,
                    float* __restrict__ out, int out_stride, int N) {
    const int h = blockIdx.y;
    const int it = blockIdx.x;
    const int i0 = it * (TILES * 16);
    const int tid = threadIdx.x;
    const int wave = tid >> 6, lane = tid & 63;
    const int n = lane & 15, q = lane >> 4;
    const int KT = N >> 5;
    const int ktn = KT / WAVES;
    const int kt0 = wave * ktn;
    const int ktend = kt0 + ktn;

    const float* s1 = s1a + (size_t)h * N;
    const float* s2 = s2a + (size_t)h * N;

    float s1v[TILES];
    const unsigned char* arow[TILES];
#pragma unroll
    for (int t = 0; t < TILES; ++t) {
        s1v[t] = s1[i0 + t * 16 + n];
        arow[t] = adjp + ((size_t)(it * TILES + t) * KT) * 64 + lane;
    }

    floatx4 acc[TILES][4];
    floatx4 accl[TILES];
#pragma unroll
    for (int t = 0; t < TILES; ++t) {
        accl[t] = (floatx4){0.f, 0.f, 0.f, 0.f};
#pragma unroll
        for (int g = 0; g < 4; ++g) acc[t][g] = (floatx4){0.f, 0.f, 0.f, 0.f};
    }

    bf16x8 ones;
    {
        short one = (n == 0) ? (short)0x3F80 : (short)0;
#pragma unroll
        for (int jj = 0; jj < 8; ++jj) ones[jj] = one;
    }

    const unsigned short* bbase = Bpk + (size_t)h * KT * 2048 + lane * 8;

    // --- prologue prefetch (kt0) ---
    bf16x8 bf_c[4];
    float4 sa_c, sb_c;
    unsigned int ab_c[TILES];
    {
        const int jb = (kt0 << 5) + (q << 3);
        sa_c = *(const float4*)(s2 + jb);
        sb_c = *(const float4*)(s2 + jb + 4);
        const unsigned short* bp = bbase + (size_t)kt0 * 2048;
#pragma unroll
        for (int g = 0; g < 4; ++g) bf_c[g] = *(const bf16x8*)(bp + g * 512);
#pragma unroll
        for (int t = 0; t < TILES; ++t) ab_c[t] = arow[t][(size_t)kt0 * 64];
    }

#pragma unroll 2
    for (int kt = kt0; kt < ktend; ++kt) {
        const int ktn1 = (kt + 1 < ktend) ? kt + 1 : kt0;
        // issue next-iteration loads
        bf16x8 bf_n[4];
        float4 sa_n, sb_n;
        unsigned int ab_n[TILES];
        {
            const int jb = (ktn1 << 5) + (q << 3);
            sa_n = *(const float4*)(s2 + jb);
            sb_n = *(const float4*)(s2 + jb + 4);
            const unsigned short* bp = bbase + (size_t)ktn1 * 2048;
#pragma unroll
            for (int g = 0; g < 4; ++g) bf_n[g] = *(const bf16x8*)(bp + g * 512);
#pragma unroll
            for (int t = 0; t < TILES; ++t) ab_n[t] = arow[t][(size_t)ktn1 * 64];
        }

        // compute with current
        const float* sv = (const float*)&sa_c;
        const float* sw = (const float*)&sb_c;
        bf16x8 af[TILES];
#pragma unroll
        for (int t = 0; t < TILES; ++t) {
            unsigned int ab = ab_c[t];
            float e[8];
#pragma unroll
            for (int jj = 0; jj < 8; ++jj) {
                float sj = (jj < 4 ? sv[jj] : sw[jj - 4]);
                float tt = s1v[t] + sj;
                float lr = fmaxf(tt, 0.2f * tt);
                lr = (ab & (1u << jj)) ? lr : -150.f;
                e[jj] = __builtin_amdgcn_exp2f(lr);
            }
            union { unsigned int u[4]; bf16x8 v; } u;
            u.u[0] = __builtin_amdgcn_perm(__float_as_uint(e[1]), __float_as_uint(e[0]), 0x07060302u);
            u.u[1] = __builtin_amdgcn_perm(__float_as_uint(e[3]), __float_as_uint(e[2]), 0x07060302u);
            u.u[2] = __builtin_amdgcn_perm(__float_as_uint(e[5]), __float_as_uint(e[4]), 0x07060302u);
            u.u[3] = __builtin_amdgcn_perm(__float_as_uint(e[7]), __float_as_uint(e[6]), 0x07060302u);
            af[t] = u.v;
        }
#pragma unroll
        for (int t = 0; t < TILES; ++t) {
#pragma unroll
            for (int g = 0; g < 4; ++g)
                acc[t][g] = __builtin_amdgcn_mfma_f32_16x16x32_bf16(af[t], bf_c[g], acc[t][g], 0, 0, 0);
            accl[t] = __builtin_amdgcn_mfma_f32_16x16x32_bf16(af[t], ones, accl[t], 0, 0, 0);
        }

        // rotate prefetch -> current
#pragma unroll
        for (int g = 0; g < 4; ++g) bf_c[g] = bf_n[g];
        sa_c = sa_n; sb_c = sb_n;
#pragma unroll
        for (int t = 0; t < TILES; ++t) ab_c[t] = ab_n[t];
    }

    // --- block-level reduction in LDS (padded stride 65) ---
    __shared__ float red[TILES * 16][65];
    __shared__ float redl[TILES * 16];
    for (int idx = tid; idx < TILES * 16 * 65; idx += WAVES * 64)
        ((float*)red)[idx] = 0.f;
    if (tid < TILES * 16) redl[tid] = 0.f;
    __syncthreads();

#pragma unroll
    for (int t = 0; t < TILES; ++t) {
#pragma unroll
        for (int g = 0; g < 4; ++g)
#pragma unroll
            for (int r = 0; r < 4; ++r)
                atomicAdd(&red[t * 16 + q * 4 + r][g * 16 + n], acc[t][g][r]);
        if (n == 0)
#pragma unroll
            for (int r = 0; r < 4; ++r)
                atomicAdd(&redl[t * 16 + q * 4 + r], accl[t][r]);
    }
    __syncthreads();

    for (int idx = tid; idx < TILES * 16 * 64; idx += WAVES * 64) {
        int row = idx >> 6, f = idx & 63;
        float lv = redl[row];
        float v = red[row][f] / fmaxf(lv, 1e-30f);
        v = v > 0.f ? v : expm1f(v);
        out[(size_t)(i0 + row) * out_stride + h * 64 + f] = v;
    }
}

// K5: Wh_out = hcat @ w_out (K=256), 8 rows per block
__global__ void whout_kernel(const float* __restrict__ hcat,
                             const float* __restrict__ w_out,
                             float* __restrict__ Wh_out, int N) {
    int tid = threadIdx.x;
    int f = tid & 63, rl = tid >> 6;
    int i0 = blockIdx.x * 8;
    __shared__ float hs[8][256];
    for (int e = tid; e < 8 * 256; e += 256)
        hs[e >> 8][e & 255] = hcat[(size_t)(i0 + (e >> 8)) * 256 + (e & 255)];
    __syncthreads();
    float a0 = 0.f, a1 = 0.f;
#pragma unroll 4
    for (int k = 0; k < 256; ++k) {
        float wv = w_out[(size_t)k * H + f];
        a0 += hs[rl][k] * wv;
        a1 += hs[rl + 4][k] * wv;
    }
    Wh_out[(size_t)(i0 + rl) * H + f] = a0;
    Wh_out[(size_t)(i0 + rl + 4) * H + f] = a1;
}

// K9: final linear + ELU, 8 rows per block
__global__ void final_kernel(const float* __restrict__ x_res,
                             const float* __restrict__ out2,
                             const float* __restrict__ outlin_w,
                             const float* __restrict__ outlin_b,
                             float* __restrict__ out, int N) {
    int tid = threadIdx.x;
    int f = tid & 63, rl = tid >> 6;
    int i0 = blockIdx.x * 8;
    __shared__ float hs[8][H];
    for (int e = tid; e < 8 * H; e += 256)
        hs[e >> 6][e & 63] = x_res[(size_t)(i0 + (e >> 6)) * H + (e & 63)] +
                             out2[(size_t)(i0 + (e >> 6)) * H + (e & 63)];
    __syncthreads();
    float b = outlin_b[f];
    float a0 = b, a1 = b;
#pragma unroll 8
    for (int k = 0; k < H; ++k) {
        float wv = outlin_w[(size_t)f * H + k];
        a0 += hs[rl][k] * wv;
        a1 += hs[rl + 4][k] * wv;
    }
    a0 = a0 > 0.f ? a0 : expm1f(a0);
    a1 = a1 > 0.f ? a1 : expm1f(a1);
    out[(size_t)(i0 + rl) * H + f] = a0;
    out[(size_t)(i0 + rl + 4) * H + f] = a1;
}

extern "C" void kernel_launch(void* const* d_in, const int* in_sizes, int n_in,
                              void* d_out, int out_size, void* d_ws, size_t ws_size,
                              hipStream_t stream) {
    const float* x        = (const float*)d_in[0];
    const int*   adj      = (const int*)d_in[1];
    const float* w_heads  = (const float*)d_in[2];
    const float* a_heads  = (const float*)d_in[3];
    const float* w_out    = (const float*)d_in[4];
    const float* a_out    = (const float*)d_in[5];
    const float* lin_w    = (const float*)d_in[6];
    const float* lin_b    = (const float*)d_in[7];
    const float* outlin_w = (const float*)d_in[8];
    const float* outlin_b = (const float*)d_in[9];
    float* out = (float*)d_out;

    const int N = in_sizes[0] / F_IN;  // 4096
    const int KT = N >> 5;             // 128

    char* p = (char*)d_ws;
    float* hcat   = (float*)p;  p += (size_t)N * 256 * 4;          // 4 MB
    float* Wh_all = (float*)p;  p += (size_t)NH * N * 64 * 4;      // 4 MB
    float* x_res  = (float*)p;  p += (size_t)N * 64 * 4;           // 1 MB
    float* Wh_out = (float*)p;  p += (size_t)N * 64 * 4;           // 1 MB
    float* out2   = (float*)p;  p += (size_t)N * 64 * 4;           // 1 MB
    float* s1h    = (float*)p;  p += (size_t)NH * N * 4;
    float* s2h    = (float*)p;  p += (size_t)NH * N * 4;
    float* s1o    = (float*)p;  p += (size_t)N * 4;
    float* s2o    = (float*)p;  p += (size_t)N * 4;
    unsigned short* Bpk  = (unsigned short*)p;  p += (size_t)NH * KT * 4 * 64 * 8 * 2;  // 2 MB
    unsigned short* BpkO = (unsigned short*)p;  p += (size_t)KT * 4 * 64 * 8 * 2;       // 512 KB
    unsigned char* adjp  = (unsigned char*)p;   p += (size_t)(N / 16) * KT * 64;        // 2 MB

    pack_adjp_kernel<<<(size_t)N * N / 256, 256, 0, stream>>>(adj, adjp, N);
    wh_kernel<<<N / 8, 256, 0, stream>>>(x, w_heads, Wh_all, N);
    xres_kernel<<<N / 8, 256, 0, stream>>>(x, lin_w, lin_b, x_res, N);
    scores_kernel<<<(NH * N + 255) / 256, 256, 0, stream>>>(Wh_all, a_heads, s1h, s2h, N, NH);
    bpack_kernel<<<dim3(KT, NH), 256, 0, stream>>>(Wh_all, Bpk, N);
    pv_mfma_kernel<2, 8><<<dim3(N / 32, NH), 512, 0, stream>>>(adjp, Bpk, s1h, s2h,
                                                               hcat, NH * H, N);
    whout_kernel<<<N / 8, 256, 0, stream>>>(hcat, w_out, Wh_out, N);
    scores_kernel<<<(N + 255) / 256, 256, 0, stream>>>(Wh_out, a_out, s1o, s2o, N, 1);
    bpack_kernel<<<dim3(KT, 1), 256, 0, stream>>>(Wh_out, BpkO, N);
    pv_mfma_kernel<1, 16><<<dim3(N / 16, 1), 1024, 0, stream>>>(adjp, BpkO, s1o, s2o,
                                                                out2, H, N);
    final_kernel<<<N / 8, 256, 0, stream>>>(x_res, out2, outlin_w, outlin_b, out, N);
}

// Round 6
// 235.668 us; speedup vs baseline: 5.2352x; 1.2048x over previous
//
#include <hip/hip_runtime.h>
#include <hip/hip_bf16.h>
#include <stdint.h>

#define F_IN 128
#define H 64
#define NH 4
#define KCH_H 4
#define KCH_O 16
#define LOG2E 1.44269504088896f

typedef __attribute__((ext_vector_type(8))) short bf16x8;
typedef __attribute__((ext_vector_type(4))) float floatx4;

// ---------------------------------------------------------------------------
// K0: read adj once (64 MB), emit bitmask bytes in pv-lane order:
// adjp[(it16*KT + kt)*64 + q*16 + n] = bits for row it16*16+n, j = kt*32+q*8..+8
__global__ void pack_adjp_kernel(const int* __restrict__ adj,
                                 unsigned char* __restrict__ adjp, int N) {
    size_t gid = (size_t)blockIdx.x * 256 + threadIdx.x;
    int v = adj[gid];
    unsigned long long m = __ballot(v > 0);
    int lane = threadIdx.x & 63;
    if ((lane & 7) == 0) {
        int b = lane >> 3;
        size_t row = gid / N;
        int j = (int)(gid - row * N);
        int kt = j >> 5, q = (j >> 3) & 3;
        int KT = N >> 5;
        adjp[((row >> 4) * (size_t)KT + kt) * 64 + q * 16 + (row & 15)] =
            (unsigned char)(m >> (b * 8));
    }
}

// K1a: Wh_all[h][i][f], 8 rows per block
__global__ void wh_kernel(const float* __restrict__ x,
                          const float* __restrict__ w_heads,
                          float* __restrict__ Wh_all, int N) {
    int tid = threadIdx.x;
    int h = tid >> 6, f = tid & 63;
    int i0 = blockIdx.x * 8;
    __shared__ float xs[8][F_IN];
    for (int e = tid; e < 8 * F_IN; e += 256)
        xs[e >> 7][e & 127] = x[(size_t)(i0 + (e >> 7)) * F_IN + (e & 127)];
    __syncthreads();
    float acc[8];
#pragma unroll
    for (int r = 0; r < 8; ++r) acc[r] = 0.f;
    const float* w = w_heads + (size_t)h * F_IN * H + f;
#pragma unroll 4
    for (int k = 0; k < F_IN; ++k) {
        float wv = w[(size_t)k * H];
#pragma unroll
        for (int r = 0; r < 8; ++r) acc[r] += xs[r][k] * wv;
    }
#pragma unroll
    for (int r = 0; r < 8; ++r)
        Wh_all[((size_t)h * N + i0 + r) * H + f] = acc[r];
}

// K1b: x_res = x @ lin_w^T + lin_b, 8 rows per block
__global__ void xres_kernel(const float* __restrict__ x,
                            const float* __restrict__ lin_w,
                            const float* __restrict__ lin_b,
                            float* __restrict__ x_res, int N) {
    int tid = threadIdx.x;
    int f = tid & 63, rl = tid >> 6;
    int i0 = blockIdx.x * 8;
    __shared__ float xs[8][F_IN];
    for (int e = tid; e < 8 * F_IN; e += 256)
        xs[e >> 7][e & 127] = x[(size_t)(i0 + (e >> 7)) * F_IN + (e & 127)];
    __syncthreads();
    float a0 = 0.f, a1 = 0.f;
#pragma unroll 4
    for (int k = 0; k < F_IN; ++k) {
        float wv = lin_w[(size_t)f * F_IN + k];
        a0 += xs[rl][k] * wv;
        a1 += xs[rl + 4][k] * wv;
    }
    float b = lin_b[f];
    x_res[(size_t)(i0 + rl) * H + f] = a0 + b;
    x_res[(size_t)(i0 + rl + 4) * H + f] = a1 + b;
}

// K2: s1/s2 = Wh . a halves, pre-scaled by log2(e)
__global__ void scores_kernel(const float* __restrict__ Wh,
                              const float* __restrict__ a,
                              float* __restrict__ s1, float* __restrict__ s2,
                              int N, int nh) {
    int idx = blockIdx.x * blockDim.x + threadIdx.x;
    if (idx >= nh * N) return;
    int h = idx / N, i = idx - h * N;
    const float* row = Wh + ((size_t)h * N + i) * H;
    const float* a1 = a + (size_t)h * 2 * H;
    const float* a2 = a1 + H;
    float acc1 = 0.f, acc2 = 0.f;
#pragma unroll 8
    for (int f = 0; f < H; ++f) {
        float v = row[f];
        acc1 += v * a1[f];
        acc2 += v * a2[f];
    }
    s1[(size_t)h * N + i] = acc1 * LOG2E;
    s2[(size_t)h * N + i] = acc2 * LOG2E;
}

// K3: pack B fragments: src[h][N][64] f32 -> Bpk[h][kt][g][lane][8] bf16
__global__ void bpack_kernel(const float* __restrict__ src,
                             unsigned short* __restrict__ dst, int N) {
    int h = blockIdx.y, kt = blockIdx.x;
    int KT = N >> 5;
    int tid = threadIdx.x;
    int g = tid >> 6, lane = tid & 63;
    int q = lane >> 4, n = lane & 15;
    const float* s = src + ((size_t)h * N + kt * 32 + q * 8) * 64 + g * 16 + n;
    unsigned short tmp[8];
#pragma unroll
    for (int jj = 0; jj < 8; ++jj) {
        __hip_bfloat16 b = __float2bfloat16(s[(size_t)jj * 64]);
        tmp[jj] = *(unsigned short*)&b;
    }
    unsigned short* d = dst + (((size_t)(h * KT + kt) * 4 + g) * 64 + lane) * 8;
#pragma unroll
    for (int jj = 0; jj < 8; ++jj) d[jj] = tmp[jj];
}

// ---------------------------------------------------------------------------
// K4: fused PV via MFMA. Block = 4 waves x 16 rows each, ALL waves step the
// same kt; B double-buffered through LDS (cooperative stage, 1 iter in
// flight); s2 chunk in LDS; adj prefetched 1-ahead. K split across blocks
// (blockIdx.z); raw partial sums + row-sum l written per chunk.
template <int KTC>
__global__ __launch_bounds__(256, 4)
void pv2_kernel(const unsigned char* __restrict__ adjp,
                const unsigned short* __restrict__ Bpk,
                const float* __restrict__ s1a,
                const float* __restrict__ s2a,
                float* __restrict__ outp, float* __restrict__ lp,
                int out_stride, int N) {
    const int h = blockIdx.y, z = blockIdx.z;
    const int KT = N >> 5;
    const int kt0 = z * KTC;
    const int tid = threadIdx.x;
    const int wave = tid >> 6, lane = tid & 63;
    const int n = lane & 15, q = lane >> 4;
    const int i0w = (blockIdx.x * 4 + wave) * 16;

    __shared__ float s2s[KTC * 32];
    __shared__ unsigned short ldsB[2][2048];

    // stage s2 chunk
    const float4* s2src = (const float4*)(s2a + (size_t)h * N + kt0 * 32);
    for (int e = tid; e < KTC * 8; e += 256) ((float4*)s2s)[e] = s2src[e];

    // stage first B tile
    const unsigned short* Bb = Bpk + ((size_t)h * KT + kt0) * 2048;
    *(uint4*)&ldsB[0][tid * 8] = *(const uint4*)(Bb + tid * 8);

    const unsigned char* ap = adjp + ((size_t)(i0w >> 4) * KT + kt0) * 64 + lane;
    unsigned int a_c = ap[0];
    const float s1v = s1a[(size_t)h * N + i0w + n];

    floatx4 acc[4];
    floatx4 accl = {0.f, 0.f, 0.f, 0.f};
#pragma unroll
    for (int g = 0; g < 4; ++g) acc[g] = (floatx4){0.f, 0.f, 0.f, 0.f};

    bf16x8 ones;
    {
        short one = (n == 0) ? (short)0x3F80 : (short)0;
#pragma unroll
        for (int jj = 0; jj < 8; ++jj) ones[jj] = one;
    }

    __syncthreads();

#pragma unroll 2
    for (int k = 0; k < KTC; ++k) {
        const int cur = k & 1;
        const int kn = (k + 1 < KTC) ? k + 1 : k;
        // issue next-tile global loads (consumed at the very end of this iter)
        uint4 bst = *(const uint4*)(Bb + (size_t)kn * 2048 + tid * 8);
        unsigned int a_n = ap[(size_t)kn * 64];

        // compute current kt from LDS
        float4 sa = *(const float4*)&s2s[k * 32 + q * 8];
        float4 sb = *(const float4*)&s2s[k * 32 + q * 8 + 4];
        const float* sv = (const float*)&sa;
        const float* sw = (const float*)&sb;
        float e[8];
#pragma unroll
        for (int jj = 0; jj < 8; ++jj) {
            float sj = (jj < 4 ? sv[jj] : sw[jj - 4]);
            float tt = s1v + sj;
            float lr = fmaxf(tt, 0.2f * tt);
            lr = (a_c & (1u << jj)) ? lr : -150.f;
            e[jj] = __builtin_amdgcn_exp2f(lr);
        }
        union { unsigned int u[4]; bf16x8 v; } u;
        u.u[0] = __builtin_amdgcn_perm(__float_as_uint(e[1]), __float_as_uint(e[0]), 0x07060302u);
        u.u[1] = __builtin_amdgcn_perm(__float_as_uint(e[3]), __float_as_uint(e[2]), 0x07060302u);
        u.u[2] = __builtin_amdgcn_perm(__float_as_uint(e[5]), __float_as_uint(e[4]), 0x07060302u);
        u.u[3] = __builtin_amdgcn_perm(__float_as_uint(e[7]), __float_as_uint(e[6]), 0x07060302u);

        bf16x8 bf0 = *(const bf16x8*)&ldsB[cur][0 * 512 + lane * 8];
        bf16x8 bf1 = *(const bf16x8*)&ldsB[cur][1 * 512 + lane * 8];
        bf16x8 bf2 = *(const bf16x8*)&ldsB[cur][2 * 512 + lane * 8];
        bf16x8 bf3 = *(const bf16x8*)&ldsB[cur][3 * 512 + lane * 8];

        acc[0] = __builtin_amdgcn_mfma_f32_16x16x32_bf16(u.v, bf0, acc[0], 0, 0, 0);
        acc[1] = __builtin_amdgcn_mfma_f32_16x16x32_bf16(u.v, bf1, acc[1], 0, 0, 0);
        acc[2] = __builtin_amdgcn_mfma_f32_16x16x32_bf16(u.v, bf2, acc[2], 0, 0, 0);
        acc[3] = __builtin_amdgcn_mfma_f32_16x16x32_bf16(u.v, bf3, acc[3], 0, 0, 0);
        accl   = __builtin_amdgcn_mfma_f32_16x16x32_bf16(u.v, ones, accl, 0, 0, 0);

        // stage next tile into the other buffer (WAR safe: separated by the
        // barrier below from next iteration's readers)
        *(uint4*)&ldsB[cur ^ 1][tid * 8] = bst;
        a_c = a_n;
        __syncthreads();
    }

    // epilogue: raw partial sums + l (no normalization here)
    float* obase = outp + ((size_t)z * N + i0w) * out_stride + h * 64;
#pragma unroll
    for (int r = 0; r < 4; ++r) {
        int rr = q * 4 + r;
        float* op = obase + (size_t)rr * out_stride + n;
        op[0]  = acc[0][r];
        op[16] = acc[1][r];
        op[32] = acc[2][r];
        op[48] = acc[3][r];
    }
    if (n == 0) {
        float* lrow = lp + ((size_t)z * gridDim.y + h) * N + i0w;
#pragma unroll
        for (int r = 0; r < 4; ++r) lrow[q * 4 + r] = accl[r];
    }
}

// K5: whout: sum KCH_H partials, normalize per (row,head), ELU, then GEMM K=256
__global__ void whout2_kernel(const float* __restrict__ hcp,  // [KCH_H][N][256]
                              const float* __restrict__ lhp,  // [KCH_H][NH][N]
                              const float* __restrict__ w_out,
                              float* __restrict__ Wh_out, int N) {
    int tid = threadIdx.x;
    int i0 = blockIdx.x * 8;
    __shared__ float hs[8][256];
    __shared__ float linv[8][NH];
    if (tid < 8 * NH) {
        int r = tid >> 2, hd = tid & 3;
        float l = 0.f;
#pragma unroll
        for (int p = 0; p < KCH_H; ++p)
            l += lhp[((size_t)p * NH + hd) * N + i0 + r];
        linv[r][hd] = 1.f / fmaxf(l, 1e-30f);
    }
    __syncthreads();
    const size_t ps = (size_t)N * 256;
    for (int e = tid; e < 8 * 256; e += 256) {
        int r = e >> 8, k = e & 255;
        size_t off = (size_t)(i0 + r) * 256 + k;
        float v = hcp[off] + hcp[ps + off] + hcp[2 * ps + off] + hcp[3 * ps + off];
        v *= linv[r][k >> 6];
        hs[r][k] = v > 0.f ? v : expm1f(v);
    }
    __syncthreads();
    int f = tid & 63, rl = tid >> 6;
    float a0 = 0.f, a1 = 0.f;
#pragma unroll 4
    for (int k = 0; k < 256; ++k) {
        float wv = w_out[(size_t)k * H + f];
        a0 += hs[rl][k] * wv;
        a1 += hs[rl + 4][k] * wv;
    }
    Wh_out[(size_t)(i0 + rl) * H + f] = a0;
    Wh_out[(size_t)(i0 + rl + 4) * H + f] = a1;
}

// K9: final: sum KCH_O partials, normalize, ELU, + x_res, GEMM, ELU
__global__ void final2_kernel(const float* __restrict__ o2p,  // [KCH_O][N][64]
                              const float* __restrict__ lop,  // [KCH_O][N]
                              const float* __restrict__ x_res,
                              const float* __restrict__ outlin_w,
                              const float* __restrict__ outlin_b,
                              float* __restrict__ out, int N) {
    int tid = threadIdx.x;
    int f = tid & 63, rl = tid >> 6;
    int i0 = blockIdx.x * 8;
    __shared__ float hs[8][H];
    __shared__ float linv[8];
    if (tid < 8) {
        float l = 0.f;
#pragma unroll
        for (int p = 0; p < KCH_O; ++p) l += lop[(size_t)p * N + i0 + tid];
        linv[tid] = 1.f / fmaxf(l, 1e-30f);
    }
    __syncthreads();
    const size_t ps = (size_t)N * 64;
    for (int e = tid; e < 8 * 64; e += 256) {
        int r = e >> 6, ff = e & 63;
        size_t off = (size_t)(i0 + r) * 64 + ff;
        float v = 0.f;
#pragma unroll
        for (int p = 0; p < KCH_O; ++p) v += o2p[p * ps + off];
        v *= linv[r];
        v = v > 0.f ? v : expm1f(v);
        hs[r][ff] = v + x_res[off];
    }
    __syncthreads();
    float b = outlin_b[f];
    float a0 = b, a1 = b;
#pragma unroll 8
    for (int k = 0; k < H; ++k) {
        float wv = outlin_w[(size_t)f * H + k];
        a0 += hs[rl][k] * wv;
        a1 += hs[rl + 4][k] * wv;
    }
    a0 = a0 > 0.f ? a0 : expm1f(a0);
    a1 = a1 > 0.f ? a1 : expm1f(a1);
    out[(size_t)(i0 + rl) * H + f] = a0;
    out[(size_t)(i0 + rl + 4) * H + f] = a1;
}

extern "C" void kernel_launch(void* const* d_in, const int* in_sizes, int n_in,
                              void* d_out, int out_size, void* d_ws, size_t ws_size,
                              hipStream_t stream) {
    const float* x        = (const float*)d_in[0];
    const int*   adj      = (const int*)d_in[1];
    const float* w_heads  = (const float*)d_in[2];
    const float* a_heads  = (const float*)d_in[3];
    const float* w_out    = (const float*)d_in[4];
    const float* a_out    = (const float*)d_in[5];
    const float* lin_w    = (const float*)d_in[6];
    const float* lin_b    = (const float*)d_in[7];
    const float* outlin_w = (const float*)d_in[8];
    const float* outlin_b = (const float*)d_in[9];
    float* out = (float*)d_out;

    const int N = in_sizes[0] / F_IN;  // 4096
    const int KT = N >> 5;             // 128
    // compile-time KTC values (problem size fixed at N=4096 -> KT=128)
    // KT/KCH_H = 32, KT/KCH_O = 8

    char* p = (char*)d_ws;
    // 16 MB partial region: hcat_part [KCH_H][N][256] aliases out2_part [KCH_O][N][64]
    float* part   = (float*)p;  p += (size_t)KCH_H * N * 256 * 4;   // 16 MB
    float* Wh_all = (float*)p;  p += (size_t)NH * N * 64 * 4;       // 4 MB
    float* x_res  = (float*)p;  p += (size_t)N * 64 * 4;            // 1 MB
    float* Wh_out = (float*)p;  p += (size_t)N * 64 * 4;            // 1 MB
    float* s1h    = (float*)p;  p += (size_t)NH * N * 4;
    float* s2h    = (float*)p;  p += (size_t)NH * N * 4;
    float* s1o    = (float*)p;  p += (size_t)N * 4;
    float* s2o    = (float*)p;  p += (size_t)N * 4;
    float* lh_part = (float*)p; p += (size_t)KCH_H * NH * N * 4;    // 256 KB
    float* lo_part = (float*)p; p += (size_t)KCH_O * N * 4;         // 256 KB
    unsigned short* Bpk  = (unsigned short*)p;  p += (size_t)NH * KT * 2048 * 2;  // 2 MB
    unsigned short* BpkO = (unsigned short*)p;  p += (size_t)KT * 2048 * 2;       // 512 KB
    unsigned char* adjp  = (unsigned char*)p;   p += (size_t)(N / 16) * KT * 64;  // 2 MB

    pack_adjp_kernel<<<(size_t)N * N / 256, 256, 0, stream>>>(adj, adjp, N);
    wh_kernel<<<N / 8, 256, 0, stream>>>(x, w_heads, Wh_all, N);
    xres_kernel<<<N / 8, 256, 0, stream>>>(x, lin_w, lin_b, x_res, N);
    scores_kernel<<<(NH * N + 255) / 256, 256, 0, stream>>>(Wh_all, a_heads, s1h, s2h, N, NH);
    bpack_kernel<<<dim3(KT, NH), 256, 0, stream>>>(Wh_all, Bpk, N);

    pv2_kernel<32><<<dim3(N / 64, NH, KCH_H), 256, 0, stream>>>(
        adjp, Bpk, s1h, s2h, part, lh_part, NH * H, N);
    whout2_kernel<<<N / 8, 256, 0, stream>>>(part, lh_part, w_out, Wh_out, N);

    scores_kernel<<<(N + 255) / 256, 256, 0, stream>>>(Wh_out, a_out, s1o, s2o, N, 1);
    bpack_kernel<<<dim3(KT, 1), 256, 0, stream>>>(Wh_out, BpkO, N);
    pv2_kernel<8><<<dim3(N / 64, 1, KCH_O), 256, 0, stream>>>(
        adjp, BpkO, s1o, s2o, part, lo_part, H, N);
    final2_kernel<<<N / 8, 256, 0, stream>>>(part, lo_part, x_res, outlin_w, outlin_b, out, N);
}

// Round 7
// 205.996 us; speedup vs baseline: 5.9893x; 1.1440x over previous
//
#include <hip/hip_runtime.h>
#include <hip/hip_bf16.h>
#include <stdint.h>

#define F_IN 128
#define H 64
#define NH 4
#define KCH_H 8
#define KCH_O 16
#define LOG2E 1.44269504088896f

typedef __attribute__((ext_vector_type(8))) short bf16x8;
typedef __attribute__((ext_vector_type(4))) float floatx4;

// ---------------------------------------------------------------------------
// K0: read adj once (64 MB) as int4 pairs; one output byte per thread.
// adjp[((row>>4)*KT + kt)*64 + q*16 + (row&15)], bit jj = adj[row][c0+jj]
__global__ void pack_adjp_kernel(const int4* __restrict__ adj4,
                                 unsigned char* __restrict__ adjp,
                                 int N, int KT) {
    int row = blockIdx.y;
    int c0 = (blockIdx.x * 256 + threadIdx.x) * 8;
    const int4* p = adj4 + ((size_t)row * N + c0) / 4;
    int4 a = p[0], b = p[1];
    unsigned int byte =
        (unsigned)(a.x > 0) | ((unsigned)(a.y > 0) << 1) |
        ((unsigned)(a.z > 0) << 2) | ((unsigned)(a.w > 0) << 3) |
        ((unsigned)(b.x > 0) << 4) | ((unsigned)(b.y > 0) << 5) |
        ((unsigned)(b.z > 0) << 6) | ((unsigned)(b.w > 0) << 7);
    int kt = c0 >> 5, q = (c0 >> 3) & 3;
    adjp[((size_t)(row >> 4) * KT + kt) * 64 + q * 16 + (row & 15)] =
        (unsigned char)byte;
}

// ---------------------------------------------------------------------------
// K1: fused per-row-block kernel: Wh_all (all 4 heads), x_res, s1h/s2h.
// 8 rows per block; wave w == head w; lane == feature f.
__global__ void wh_fused_kernel(const float* __restrict__ x,
                                const float* __restrict__ w_heads,
                                const float* __restrict__ a_heads,
                                const float* __restrict__ lin_w,
                                const float* __restrict__ lin_b,
                                float* __restrict__ Wh_all,
                                float* __restrict__ x_res,
                                float* __restrict__ s1h,
                                float* __restrict__ s2h, int N) {
    int tid = threadIdx.x;
    int h = tid >> 6, f = tid & 63;
    int i0 = blockIdx.x * 8;
    __shared__ float xs[8][F_IN];
    for (int e = tid; e < 8 * F_IN; e += 256)
        xs[e >> 7][e & 127] = x[(size_t)(i0 + (e >> 7)) * F_IN + (e & 127)];
    __syncthreads();
    float acc[8];
#pragma unroll
    for (int r = 0; r < 8; ++r) acc[r] = 0.f;
    float xr0 = 0.f, xr1 = 0.f;
    const float* w = w_heads + (size_t)h * F_IN * H + f;
    const float* lw = lin_w + (size_t)f * F_IN;
#pragma unroll 4
    for (int k = 0; k < F_IN; ++k) {
        float wv = w[(size_t)k * H];
#pragma unroll
        for (int r = 0; r < 8; ++r) acc[r] += xs[r][k] * wv;
        float wx = lw[k];
        xr0 += xs[h][k] * wx;
        xr1 += xs[h + 4][k] * wx;
    }
#pragma unroll
    for (int r = 0; r < 8; ++r)
        Wh_all[((size_t)h * N + i0 + r) * H + f] = acc[r];
    // x_res (rows i0+h, i0+h+4)
    float b = lin_b[f];
    x_res[(size_t)(i0 + h) * H + f] = xr0 + b;
    x_res[(size_t)(i0 + h + 4) * H + f] = xr1 + b;
    // scores: wave-butterfly reduce acc[r]*a over lanes (f)
    float a1v = a_heads[(size_t)h * 2 * H + f];
    float a2v = a_heads[(size_t)h * 2 * H + H + f];
#pragma unroll
    for (int r = 0; r < 8; ++r) {
        float t1 = acc[r] * a1v;
        float t2 = acc[r] * a2v;
#pragma unroll
        for (int off = 32; off > 0; off >>= 1) {
            t1 += __shfl_xor(t1, off, 64);
            t2 += __shfl_xor(t2, off, 64);
        }
        if (f == 0) {
            s1h[(size_t)h * N + i0 + r] = t1 * LOG2E;
            s2h[(size_t)h * N + i0 + r] = t2 * LOG2E;
        }
    }
}

// K3: pack B fragments: src[h][N][64] f32 -> Bpk[h][kt][g][lane][8] bf16
__global__ void bpack_kernel(const float* __restrict__ src,
                             unsigned short* __restrict__ dst, int N) {
    int h = blockIdx.y, kt = blockIdx.x;
    int KT = N >> 5;
    int tid = threadIdx.x;
    int g = tid >> 6, lane = tid & 63;
    int q = lane >> 4, n = lane & 15;
    const float* s = src + ((size_t)h * N + kt * 32 + q * 8) * 64 + g * 16 + n;
    unsigned short tmp[8];
#pragma unroll
    for (int jj = 0; jj < 8; ++jj) {
        __hip_bfloat16 b = __float2bfloat16(s[(size_t)jj * 64]);
        tmp[jj] = *(unsigned short*)&b;
    }
    unsigned short* d = dst + (((size_t)(h * KT + kt) * 4 + g) * 64 + lane) * 8;
#pragma unroll
    for (int jj = 0; jj < 8; ++jj) d[jj] = tmp[jj];
}

// ---------------------------------------------------------------------------
// K4: fused PV via MFMA. Block = 4 waves x 16 rows, block-uniform kt, B
// double-buffered in LDS, K split across blockIdx.z; raw partials + l out.
template <int KTC>
__global__ __launch_bounds__(256, 8)
void pv2_kernel(const unsigned char* __restrict__ adjp,
                const unsigned short* __restrict__ Bpk,
                const float* __restrict__ s1a,
                const float* __restrict__ s2a,
                float* __restrict__ outp, float* __restrict__ lp,
                int out_stride, int N) {
    const int h = blockIdx.y, z = blockIdx.z;
    const int KT = N >> 5;
    const int kt0 = z * KTC;
    const int tid = threadIdx.x;
    const int wave = tid >> 6, lane = tid & 63;
    const int n = lane & 15, q = lane >> 4;
    const int i0w = (blockIdx.x * 4 + wave) * 16;

    __shared__ float s2s[KTC * 32];
    __shared__ unsigned short ldsB[2][2048];

    const float4* s2src = (const float4*)(s2a + (size_t)h * N + kt0 * 32);
    for (int e = tid; e < KTC * 8; e += 256) ((float4*)s2s)[e] = s2src[e];

    const unsigned short* Bb = Bpk + ((size_t)h * KT + kt0) * 2048;
    *(uint4*)&ldsB[0][tid * 8] = *(const uint4*)(Bb + tid * 8);

    const unsigned char* ap = adjp + ((size_t)(i0w >> 4) * KT + kt0) * 64 + lane;
    unsigned int a_c = ap[0];
    const float s1v = s1a[(size_t)h * N + i0w + n];

    floatx4 acc[4];
    floatx4 accl = {0.f, 0.f, 0.f, 0.f};
#pragma unroll
    for (int g = 0; g < 4; ++g) acc[g] = (floatx4){0.f, 0.f, 0.f, 0.f};

    bf16x8 ones;
    {
        short one = (n == 0) ? (short)0x3F80 : (short)0;
#pragma unroll
        for (int jj = 0; jj < 8; ++jj) ones[jj] = one;
    }

    __syncthreads();

#pragma unroll 2
    for (int k = 0; k < KTC; ++k) {
        const int cur = k & 1;
        const int kn = (k + 1 < KTC) ? k + 1 : k;
        uint4 bst = *(const uint4*)(Bb + (size_t)kn * 2048 + tid * 8);
        unsigned int a_n = ap[(size_t)kn * 64];

        float4 sa = *(const float4*)&s2s[k * 32 + q * 8];
        float4 sb = *(const float4*)&s2s[k * 32 + q * 8 + 4];
        const float* sv = (const float*)&sa;
        const float* sw = (const float*)&sb;
        float e[8];
#pragma unroll
        for (int jj = 0; jj < 8; ++jj) {
            float sj = (jj < 4 ? sv[jj] : sw[jj - 4]);
            float tt = s1v + sj;
            float lr = fmaxf(tt, 0.2f * tt);
            lr = (a_c & (1u << jj)) ? lr : -150.f;
            e[jj] = __builtin_amdgcn_exp2f(lr);
        }
        union { unsigned int u[4]; bf16x8 v; } u;
        u.u[0] = __builtin_amdgcn_perm(__float_as_uint(e[1]), __float_as_uint(e[0]), 0x07060302u);
        u.u[1] = __builtin_amdgcn_perm(__float_as_uint(e[3]), __float_as_uint(e[2]), 0x07060302u);
        u.u[2] = __builtin_amdgcn_perm(__float_as_uint(e[5]), __float_as_uint(e[4]), 0x07060302u);
        u.u[3] = __builtin_amdgcn_perm(__float_as_uint(e[7]), __float_as_uint(e[6]), 0x07060302u);

        bf16x8 bf0 = *(const bf16x8*)&ldsB[cur][0 * 512 + lane * 8];
        bf16x8 bf1 = *(const bf16x8*)&ldsB[cur][1 * 512 + lane * 8];
        bf16x8 bf2 = *(const bf16x8*)&ldsB[cur][2 * 512 + lane * 8];
        bf16x8 bf3 = *(const bf16x8*)&ldsB[cur][3 * 512 + lane * 8];

        acc[0] = __builtin_amdgcn_mfma_f32_16x16x32_bf16(u.v, bf0, acc[0], 0, 0, 0);
        acc[1] = __builtin_amdgcn_mfma_f32_16x16x32_bf16(u.v, bf1, acc[1], 0, 0, 0);
        acc[2] = __builtin_amdgcn_mfma_f32_16x16x32_bf16(u.v, bf2, acc[2], 0, 0, 0);
        acc[3] = __builtin_amdgcn_mfma_f32_16x16x32_bf16(u.v, bf3, acc[3], 0, 0, 0);
        accl   = __builtin_amdgcn_mfma_f32_16x16x32_bf16(u.v, ones, accl, 0, 0, 0);

        *(uint4*)&ldsB[cur ^ 1][tid * 8] = bst;
        a_c = a_n;
        __syncthreads();
    }

    float* obase = outp + ((size_t)z * N + i0w) * out_stride + h * 64;
#pragma unroll
    for (int r = 0; r < 4; ++r) {
        int rr = q * 4 + r;
        float* op = obase + (size_t)rr * out_stride + n;
        op[0]  = acc[0][r];
        op[16] = acc[1][r];
        op[32] = acc[2][r];
        op[48] = acc[3][r];
    }
    if (n == 0) {
        float* lrow = lp + ((size_t)z * gridDim.y + h) * N + i0w;
#pragma unroll
        for (int r = 0; r < 4; ++r) lrow[q * 4 + r] = accl[r];
    }
}

// K5: whout: sum KCH_H partials, normalize, ELU, GEMM K=256, + scores_o fold
__global__ void whout2_kernel(const float* __restrict__ hcp,  // [KCH_H][N][256]
                              const float* __restrict__ lhp,  // [KCH_H][NH][N]
                              const float* __restrict__ w_out,
                              const float* __restrict__ a_out,
                              float* __restrict__ Wh_out,
                              float* __restrict__ s1o,
                              float* __restrict__ s2o, int N) {
    int tid = threadIdx.x;
    int i0 = blockIdx.x * 8;
    __shared__ float hs[8][256];
    __shared__ float linv[8][NH];
    if (tid < 8 * NH) {
        int r = tid >> 2, hd = tid & 3;
        float l = 0.f;
#pragma unroll
        for (int p = 0; p < KCH_H; ++p)
            l += lhp[((size_t)p * NH + hd) * N + i0 + r];
        linv[r][hd] = 1.f / fmaxf(l, 1e-30f);
    }
    __syncthreads();
    const size_t ps = (size_t)N * 256;
    for (int e = tid; e < 8 * 256; e += 256) {
        int r = e >> 8, k = e & 255;
        size_t off = (size_t)(i0 + r) * 256 + k;
        float v = 0.f;
#pragma unroll
        for (int p = 0; p < KCH_H; ++p) v += hcp[p * ps + off];
        v *= linv[r][k >> 6];
        hs[r][k] = v > 0.f ? v : expm1f(v);
    }
    __syncthreads();
    int f = tid & 63, rl = tid >> 6;
    float a0 = 0.f, a1 = 0.f;
#pragma unroll 4
    for (int k = 0; k < 256; ++k) {
        float wv = w_out[(size_t)k * H + f];
        a0 += hs[rl][k] * wv;
        a1 += hs[rl + 4][k] * wv;
    }
    Wh_out[(size_t)(i0 + rl) * H + f] = a0;
    Wh_out[(size_t)(i0 + rl + 4) * H + f] = a1;
    // fold scores_o: wave rl covers rows (rl, rl+4), lane == f
    float w1 = a_out[f], w2 = a_out[H + f];
    float t10 = a0 * w1, t20 = a0 * w2, t11 = a1 * w1, t21 = a1 * w2;
#pragma unroll
    for (int off = 32; off > 0; off >>= 1) {
        t10 += __shfl_xor(t10, off, 64);
        t20 += __shfl_xor(t20, off, 64);
        t11 += __shfl_xor(t11, off, 64);
        t21 += __shfl_xor(t21, off, 64);
    }
    if (f == 0) {
        s1o[i0 + rl] = t10 * LOG2E;
        s2o[i0 + rl] = t20 * LOG2E;
        s1o[i0 + rl + 4] = t11 * LOG2E;
        s2o[i0 + rl + 4] = t21 * LOG2E;
    }
}

// K9: final: sum KCH_O partials, normalize, ELU, + x_res, GEMM, ELU
__global__ void final2_kernel(const float* __restrict__ o2p,  // [KCH_O][N][64]
                              const float* __restrict__ lop,  // [KCH_O][N]
                              const float* __restrict__ x_res,
                              const float* __restrict__ outlin_w,
                              const float* __restrict__ outlin_b,
                              float* __restrict__ out, int N) {
    int tid = threadIdx.x;
    int f = tid & 63, rl = tid >> 6;
    int i0 = blockIdx.x * 8;
    __shared__ float hs[8][H];
    __shared__ float linv[8];
    if (tid < 8) {
        float l = 0.f;
#pragma unroll
        for (int p = 0; p < KCH_O; ++p) l += lop[(size_t)p * N + i0 + tid];
        linv[tid] = 1.f / fmaxf(l, 1e-30f);
    }
    __syncthreads();
    const size_t ps = (size_t)N * 64;
    for (int e = tid; e < 8 * 64; e += 256) {
        int r = e >> 6, ff = e & 63;
        size_t off = (size_t)(i0 + r) * 64 + ff;
        float v = 0.f;
#pragma unroll
        for (int p = 0; p < KCH_O; ++p) v += o2p[p * ps + off];
        v *= linv[r];
        v = v > 0.f ? v : expm1f(v);
        hs[r][ff] = v + x_res[off];
    }
    __syncthreads();
    float b = outlin_b[f];
    float a0 = b, a1 = b;
#pragma unroll 8
    for (int k = 0; k < H; ++k) {
        float wv = outlin_w[(size_t)f * H + k];
        a0 += hs[rl][k] * wv;
        a1 += hs[rl + 4][k] * wv;
    }
    a0 = a0 > 0.f ? a0 : expm1f(a0);
    a1 = a1 > 0.f ? a1 : expm1f(a1);
    out[(size_t)(i0 + rl) * H + f] = a0;
    out[(size_t)(i0 + rl + 4) * H + f] = a1;
}

extern "C" void kernel_launch(void* const* d_in, const int* in_sizes, int n_in,
                              void* d_out, int out_size, void* d_ws, size_t ws_size,
                              hipStream_t stream) {
    const float* x        = (const float*)d_in[0];
    const int*   adj      = (const int*)d_in[1];
    const float* w_heads  = (const float*)d_in[2];
    const float* a_heads  = (const float*)d_in[3];
    const float* w_out    = (const float*)d_in[4];
    const float* a_out    = (const float*)d_in[5];
    const float* lin_w    = (const float*)d_in[6];
    const float* lin_b    = (const float*)d_in[7];
    const float* outlin_w = (const float*)d_in[8];
    const float* outlin_b = (const float*)d_in[9];
    float* out = (float*)d_out;

    const int N = in_sizes[0] / F_IN;  // 4096
    const int KT = N >> 5;             // 128

    char* p = (char*)d_ws;
    // partial region: hcat_part [KCH_H][N][256] aliases out2_part [KCH_O][N][64]
    float* part   = (float*)p;  p += (size_t)KCH_H * N * 256 * 4;   // 32 MB
    float* Wh_all = (float*)p;  p += (size_t)NH * N * 64 * 4;       // 4 MB
    float* x_res  = (float*)p;  p += (size_t)N * 64 * 4;            // 1 MB
    float* Wh_out = (float*)p;  p += (size_t)N * 64 * 4;            // 1 MB
    float* s1h    = (float*)p;  p += (size_t)NH * N * 4;
    float* s2h    = (float*)p;  p += (size_t)NH * N * 4;
    float* s1o    = (float*)p;  p += (size_t)N * 4;
    float* s2o    = (float*)p;  p += (size_t)N * 4;
    float* lh_part = (float*)p; p += (size_t)KCH_H * NH * N * 4;
    float* lo_part = (float*)p; p += (size_t)KCH_O * N * 4;
    unsigned short* Bpk  = (unsigned short*)p;  p += (size_t)NH * KT * 2048 * 2;  // 2 MB
    unsigned short* BpkO = (unsigned short*)p;  p += (size_t)KT * 2048 * 2;       // 512 KB
    unsigned char* adjp  = (unsigned char*)p;   p += (size_t)(N / 16) * KT * 64;  // 2 MB

    pack_adjp_kernel<<<dim3(N / 2048, N), 256, 0, stream>>>((const int4*)adj, adjp, N, KT);
    wh_fused_kernel<<<N / 8, 256, 0, stream>>>(x, w_heads, a_heads, lin_w, lin_b,
                                               Wh_all, x_res, s1h, s2h, N);
    bpack_kernel<<<dim3(KT, NH), 256, 0, stream>>>(Wh_all, Bpk, N);

    pv2_kernel<16><<<dim3(N / 64, NH, KCH_H), 256, 0, stream>>>(
        adjp, Bpk, s1h, s2h, part, lh_part, NH * H, N);
    whout2_kernel<<<N / 8, 256, 0, stream>>>(part, lh_part, w_out, a_out,
                                             Wh_out, s1o, s2o, N);
    bpack_kernel<<<dim3(KT, 1), 256, 0, stream>>>(Wh_out, BpkO, N);
    pv2_kernel<8><<<dim3(N / 64, 1, KCH_O), 256, 0, stream>>>(
        adjp, BpkO, s1o, s2o, part, lo_part, H, N);
    final2_kernel<<<N / 8, 256, 0, stream>>>(part, lo_part, x_res, outlin_w, outlin_b, out, N);
}